// Round 1
// baseline (18.174 us; speedup 1.0000x reference)
//
#include <hip/hip_runtime.h>

#define NB 4096
#define TPB 256
#define NSPLIT 32
#define CHUNK (NB / NSPLIT)   // 128

// Partial accumulation: block (kb, s) handles bodies k in [kb*256, kb*256+256)
// against sources i in [s*128, s*128+128). Writes float2 partial per (s, k).
__global__ __launch_bounds__(TPB) void nbody_partial(
    const float* __restrict__ x, const float* __restrict__ m,
    float* __restrict__ ws)
{
    const int tid = threadIdx.x;
    const int k   = blockIdx.x * TPB + tid;
    const int s   = blockIdx.y;
    const int i0  = s * CHUNK;

    __shared__ float sqx[CHUNK], sqy[CHUNK], sm[CHUNK];
    if (tid < CHUNK) {
        const int i = i0 + tid;
        const float4 xi = ((const float4*)x)[i];
        sqx[tid] = xi.x; sqy[tid] = xi.y; sm[tid] = m[i];
    }
    __syncthreads();

    const float4 xk = ((const float4*)x)[k];
    const float qx = xk.x, qy = xk.y;
    float ax = 0.f, ay = 0.f;

    #pragma unroll 8
    for (int ii = 0; ii < CHUNK; ++ii) {
        const int i = i0 + ii;
        const int d = k - i;
        const float dx = qx - sqx[ii];
        const float dy = qy - sqy[ii];
        float sq = fmaf(dx, dx, dy * dy);
        sq = (d == 0) ? 1.0f : sq;            // keep rsqrt finite on self-pair
        const float rinv = rsqrtf(sq);
        float w = rinv * rinv * rinv * sm[ii];
        // c = 0 (self), 2 (adjacent pair counted in tril AND superdiag), 1 otherwise
        const float c = (d == 0) ? 0.f : ((d == 1 || d == -1) ? 2.f : 1.f);
        w *= c;
        ax = fmaf(dx, w, ax);
        ay = fmaf(dy, w, ay);
    }

    const float mk = m[k];                    // mu = G*m_k*m_i, G=1, m_k factored out
    ((float2*)ws)[s * NB + k] = make_float2(ax * mk, ay * mk);
}

// Reduce the NSPLIT partials and assemble output: out[k] = (p/m0, acc)
__global__ __launch_bounds__(TPB) void nbody_reduce(
    const float* __restrict__ x, const float* __restrict__ m,
    const float* __restrict__ ws, float* __restrict__ out)
{
    const int k = blockIdx.x * TPB + threadIdx.x;
    const float2* wsp = (const float2*)ws;
    float ax = 0.f, ay = 0.f;
    #pragma unroll
    for (int s = 0; s < NSPLIT; ++s) {
        const float2 v = wsp[s * NB + k];
        ax += v.x; ay += v.y;
    }
    const float4 xk = ((const float4*)x)[k];
    const float m0inv = 1.0f / m[0];
    float4 o;
    o.x = xk.z * m0inv;   // dH/dp = p / m0
    o.y = xk.w * m0inv;
    o.z = ax;             // -dH/dq
    o.w = ay;
    ((float4*)out)[k] = o;
}

// Fallback if workspace is too small: single-pass, 16 blocks, full i-loop.
__global__ __launch_bounds__(TPB) void nbody_full(
    const float* __restrict__ x, const float* __restrict__ m,
    float* __restrict__ out)
{
    const int tid = threadIdx.x;
    const int k   = blockIdx.x * TPB + tid;
    __shared__ float sqx[TPB], sqy[TPB], sm[TPB];

    const float4 xk = ((const float4*)x)[k];
    const float qx = xk.x, qy = xk.y;
    float ax = 0.f, ay = 0.f;

    for (int t = 0; t < NB / TPB; ++t) {
        __syncthreads();
        const int i = t * TPB + tid;
        const float4 xi = ((const float4*)x)[i];
        sqx[tid] = xi.x; sqy[tid] = xi.y; sm[tid] = m[i];
        __syncthreads();
        for (int ii = 0; ii < TPB; ++ii) {
            const int gi = t * TPB + ii;
            const int d = k - gi;
            const float dx = qx - sqx[ii];
            const float dy = qy - sqy[ii];
            float sq = fmaf(dx, dx, dy * dy);
            sq = (d == 0) ? 1.0f : sq;
            const float rinv = rsqrtf(sq);
            float w = rinv * rinv * rinv * sm[ii];
            const float c = (d == 0) ? 0.f : ((d == 1 || d == -1) ? 2.f : 1.f);
            w *= c;
            ax = fmaf(dx, w, ax);
            ay = fmaf(dy, w, ay);
        }
    }
    const float mk = m[k];
    const float m0inv = 1.0f / m[0];
    float4 o;
    o.x = xk.z * m0inv;
    o.y = xk.w * m0inv;
    o.z = ax * mk;
    o.w = ay * mk;
    ((float4*)out)[k] = o;
}

extern "C" void kernel_launch(void* const* d_in, const int* in_sizes, int n_in,
                              void* d_out, int out_size, void* d_ws, size_t ws_size,
                              hipStream_t stream) {
    const float* x = (const float*)d_in[0];
    const float* m = (const float*)d_in[1];
    float* out = (float*)d_out;

    const size_t needed = (size_t)NSPLIT * NB * 2 * sizeof(float);
    if (ws_size >= needed) {
        dim3 grid(NB / TPB, NSPLIT);
        nbody_partial<<<grid, dim3(TPB), 0, stream>>>(x, m, (float*)d_ws);
        nbody_reduce<<<dim3(NB / TPB), dim3(TPB), 0, stream>>>(x, m, (float*)d_ws, out);
    } else {
        nbody_full<<<dim3(NB / TPB), dim3(TPB), 0, stream>>>(x, m, out);
    }
}